// Round 1
// baseline (38.572 us; speedup 1.0000x reference)
//
#include <hip/hip_runtime.h>
#include <math.h>

// Problem geometry (fixed by the reference setup)
#define CH       48
#define DIM      64
#define SPATIAL  (DIM * DIM * DIM)   // 262144 per (b, c)
#define NB       2
#define VOL      (NB * SPATIAL)      // 524288 per scale volume
#define NSCALES  3

// -------------------------------------------------------------------------
// K1: channel reduction.  z_s[b, sp] = sum_c fuse_w[s*CH + c] * x[b, c, sp]
// float4-vectorized over the spatial index; x is read exactly once (100.7 MB).
// -------------------------------------------------------------------------
__global__ __launch_bounds__(256) void k_chanred(
        const float* __restrict__ x,
        const float* __restrict__ fw,
        float* __restrict__ z) {
    __shared__ float sw[NSCALES * CH];
    if (threadIdx.x < NSCALES * CH) sw[threadIdx.x] = fw[threadIdx.x];
    __syncthreads();

    int gid = blockIdx.x * blockDim.x + threadIdx.x;   // 0 .. VOL/4-1
    int b   = gid >> 16;                               // SPATIAL/4 = 65536 = 2^16
    int sp4 = gid & 0xFFFF;

    const float4* xb = (const float4*)x + (size_t)b * (CH * (SPATIAL / 4)) + sp4;

    float4 a0 = make_float4(0.f, 0.f, 0.f, 0.f);
    float4 a1 = make_float4(0.f, 0.f, 0.f, 0.f);
    float4 a2 = make_float4(0.f, 0.f, 0.f, 0.f);

    #pragma unroll 4
    for (int c = 0; c < CH; ++c) {
        float4 v = xb[(size_t)c * (SPATIAL / 4)];
        float w0 = sw[c], w1 = sw[CH + c], w2 = sw[2 * CH + c];
        a0.x += w0 * v.x; a0.y += w0 * v.y; a0.z += w0 * v.z; a0.w += w0 * v.w;
        a1.x += w1 * v.x; a1.y += w1 * v.y; a1.z += w1 * v.z; a1.w += w1 * v.w;
        a2.x += w2 * v.x; a2.y += w2 * v.y; a2.z += w2 * v.z; a2.w += w2 * v.w;
    }

    float4* z4 = (float4*)z;
    size_t o = (size_t)b * (SPATIAL / 4) + sp4;
    z4[o]                 = a0;
    z4[(VOL / 4) + o]     = a1;
    z4[2 * (VOL / 4) + o] = a2;
}

// -------------------------------------------------------------------------
// K2: box-sum along W (innermost axis), zero padding, all 3 scales.
// k = 3 + 2*s, pad p = s+1.  Window clipped to [0,63]; outside = 0.
// -------------------------------------------------------------------------
__global__ __launch_bounds__(256) void k_poolw(
        const float* __restrict__ in, float* __restrict__ out) {
    int gid = blockIdx.x * blockDim.x + threadIdx.x;   // 0 .. 3*VOL-1
    int s   = gid >> 19;                               // VOL = 2^19
    int w0  = gid & 63;
    int p   = s + 1;
    const float* row = in + (gid - w0);
    int lo = w0 - p; if (lo < 0)  lo = 0;
    int hi = w0 + p; if (hi > 63) hi = 63;
    float acc = 0.f;
    for (int w = lo; w <= hi; ++w) acc += row[w];
    out[gid] = acc;
}

// -------------------------------------------------------------------------
// K3: box-sum along H (stride 64).
// -------------------------------------------------------------------------
__global__ __launch_bounds__(256) void k_poolh(
        const float* __restrict__ in, float* __restrict__ out) {
    int gid = blockIdx.x * blockDim.x + threadIdx.x;
    int s   = gid >> 19;
    int h0  = (gid >> 6) & 63;
    int p   = s + 1;
    const float* col = in + (gid - (h0 << 6));
    int lo = h0 - p; if (lo < 0)  lo = 0;
    int hi = h0 + p; if (hi > 63) hi = 63;
    float acc = 0.f;
    for (int h = lo; h <= hi; ++h) acc += col[h << 6];
    out[gid] = acc;
}

// -------------------------------------------------------------------------
// K4: box-sum along D (stride 4096) + 1/k^3 scaling + cross-scale sum
//     + bias + sigmoid.  Writes the final (B,1,D,H,W) output.
// -------------------------------------------------------------------------
__global__ __launch_bounds__(256) void k_poold_fuse(
        const float* __restrict__ in,
        const float* __restrict__ fb,
        float* __restrict__ out) {
    int gid = blockIdx.x * blockDim.x + threadIdx.x;   // 0 .. VOL-1
    int d0  = (gid >> 12) & 63;

    const float inv[NSCALES] = {1.f / 27.f, 1.f / 125.f, 1.f / 343.f};
    float acc = fb[0];

    #pragma unroll
    for (int s = 0; s < NSCALES; ++s) {
        int p  = s + 1;
        int lo = d0 - p; if (lo < 0)  lo = 0;
        int hi = d0 + p; if (hi > 63) hi = 63;
        const float* base = in + (size_t)s * VOL + (gid - (d0 << 12));
        float a = 0.f;
        for (int d = lo; d <= hi; ++d) a += base[d << 12];
        acc += a * inv[s];
    }
    out[gid] = 1.f / (1.f + __expf(-acc));
}

// -------------------------------------------------------------------------
extern "C" void kernel_launch(void* const* d_in, const int* in_sizes, int n_in,
                              void* d_out, int out_size, void* d_ws, size_t ws_size,
                              hipStream_t stream) {
    const float* x  = (const float*)d_in[0];   // (2, 48, 64, 64, 64) f32
    const float* fw = (const float*)d_in[1];   // (1, 144) f32
    const float* fb = (const float*)d_in[2];   // (1,) f32
    float* out = (float*)d_out;                // (2, 1, 64, 64, 64) f32

    float* ws0 = (float*)d_ws;                 // 3*VOL floats = 6.29 MB
    float* ws1 = ws0 + (size_t)NSCALES * VOL;  // another 6.29 MB

    // K1: channel mix -> ws0   (reads x once: 100.7 MB)
    k_chanred<<<(VOL / 4) / 256, 256, 0, stream>>>(x, fw, ws0);
    // K2: box along W -> ws1
    k_poolw<<<(NSCALES * VOL) / 256, 256, 0, stream>>>(ws0, ws1);
    // K3: box along H -> ws0
    k_poolh<<<(NSCALES * VOL) / 256, 256, 0, stream>>>(ws1, ws0);
    // K4: box along D + scale + bias + sigmoid -> out
    k_poold_fuse<<<VOL / 256, 256, 0, stream>>>(ws0, fb, out);
}

// Round 3
// 32.843 us; speedup vs baseline: 1.1744x; 1.1744x over previous
//
#include <hip/hip_runtime.h>
#include <math.h>

// Problem geometry (fixed by the reference setup)
#define CH       48
#define DIM      64
#define SPATIAL  (DIM * DIM * DIM)   // 262144 per (b, c)
#define NB       2
#define VOL      (NB * SPATIAL)      // 524288 per scale volume
#define NS       3
#define ROWS     16                  // W-rows per block in kernel A

// Native vector type (works with __builtin_nontemporal_*)
typedef float f4 __attribute__((ext_vector_type(4)));

// -------------------------------------------------------------------------
// A: channel reduction + W box-sum, fused.
//   z_s[b,d,h,w] = sum_{w'} sum_c fuse_w[s*CH+c] * x[b,c,d,h,w']
// Block = 256 threads = 16 rows x 16 lanes (each lane owns a float4 of W).
// x is read exactly once (100.7 MB, non-temporal). W-pool runs in LDS with
// lane-consecutive 16B reads (conflict-free ds_read_b128).
// -------------------------------------------------------------------------
__global__ __launch_bounds__(256) void k_chanred_wpool(
        const float* __restrict__ x,
        const float* __restrict__ fw,
        float* __restrict__ z) {
    __shared__ float sw[NS * CH];
    __shared__ f4 tile[NS][ROWS][16];        // 12 KB
    const int tid = threadIdx.x;
    if (tid < NS * CH) sw[tid] = fw[tid];
    __syncthreads();

    const int lr  = tid >> 4;                // row in block, 0..15
    const int lw  = tid & 15;                // float4 index along W, 0..15
    const int row = blockIdx.x * ROWS + lr;  // 0..8191  (= b*4096 + d*64 + h)
    const int b   = row >> 12;

    const f4* xp = (const f4*)x
        + (size_t)b * CH * (SPATIAL / 4)
        + (size_t)(row & 4095) * 16 + lw;

    f4 a0 = {0,0,0,0}, a1 = {0,0,0,0}, a2 = {0,0,0,0};
    #pragma unroll 8
    for (int c = 0; c < CH; ++c) {
        f4 v = __builtin_nontemporal_load(&xp[(size_t)c * (SPATIAL / 4)]);
        a0 += sw[c] * v;
        a1 += sw[CH + c] * v;
        a2 += sw[2 * CH + c] * v;
    }
    tile[0][lr][lw] = a0;
    tile[1][lr][lw] = a1;
    tile[2][lr][lw] = a2;
    __syncthreads();

    f4* z4 = (f4*)z;
    const size_t ob = (size_t)row * 16 + lw;
    const f4 zero = {0,0,0,0};
    #pragma unroll
    for (int s = 0; s < NS; ++s) {
        // 12-float window around this lane's 4 outputs; zero-fill past the
        // row ends == the reference's zero padding (count_include_pad).
        f4 m1 = (lw > 0)  ? tile[s][lr][lw - 1] : zero;
        f4 m0 = tile[s][lr][lw];
        f4 p1 = (lw < 15) ? tile[s][lr][lw + 1] : zero;
        float f[12] = {m1.x, m1.y, m1.z, m1.w,
                       m0.x, m0.y, m0.z, m0.w,
                       p1.x, p1.y, p1.z, p1.w};
        const int p = s + 1;
        f4 r;
        #pragma unroll
        for (int j = 0; j < 4; ++j) {
            float acc = 0.f;
            #pragma unroll
            for (int i = -3; i <= 3; ++i)
                if (i >= -p && i <= p) acc += f[4 + j + i];
            r[j] = acc;
        }
        z4[(size_t)s * (VOL / 4) + ob] = r;
    }
}

// -------------------------------------------------------------------------
// B: box-sum along H (stride 16 float4), all 3 scales, float4-vectorized.
// -------------------------------------------------------------------------
__global__ __launch_bounds__(256) void k_poolh(
        const float* __restrict__ in, float* __restrict__ out) {
    int gid = blockIdx.x * blockDim.x + threadIdx.x;   // 0 .. 3*VOL/4-1
    int s   = gid >> 17;                               // VOL/4 = 2^17
    int r   = gid & 0x1FFFF;
    int h   = (r >> 4) & 63;
    int p   = s + 1;
    const f4* col = (const f4*)in + ((size_t)s << 17) + (r - (h << 4));
    int lo = h - p; if (lo < 0)  lo = 0;
    int hi = h + p; if (hi > 63) hi = 63;
    f4 a = {0,0,0,0};
    for (int hh = lo; hh <= hi; ++hh) a += col[hh << 4];
    ((f4*)out)[gid] = a;
}

// -------------------------------------------------------------------------
// C: box-sum along D (stride 1024 float4) + 1/k^3 + cross-scale sum
//    + bias + sigmoid.  float4-vectorized, non-temporal output store.
// -------------------------------------------------------------------------
__global__ __launch_bounds__(256) void k_poold_fuse(
        const float* __restrict__ in,
        const float* __restrict__ fb,
        float* __restrict__ out) {
    int gid = blockIdx.x * blockDim.x + threadIdx.x;   // 0 .. VOL/4-1
    int d   = (gid >> 10) & 63;
    int base = gid - (d << 10);
    const float inv[NS] = {1.f / 27.f, 1.f / 125.f, 1.f / 343.f};
    const float bias = fb[0];
    f4 acc = {bias, bias, bias, bias};
    #pragma unroll
    for (int s = 0; s < NS; ++s) {
        int p  = s + 1;
        int lo = d - p; if (lo < 0)  lo = 0;
        int hi = d + p; if (hi > 63) hi = 63;
        const f4* bp = (const f4*)in + ((size_t)s << 17) + base;
        f4 a = {0,0,0,0};
        for (int dd = lo; dd <= hi; ++dd) a += bp[dd << 10];
        acc += a * inv[s];
    }
    f4 r;
    #pragma unroll
    for (int j = 0; j < 4; ++j) r[j] = 1.f / (1.f + __expf(-acc[j]));
    __builtin_nontemporal_store(r, &((f4*)out)[gid]);
}

// -------------------------------------------------------------------------
extern "C" void kernel_launch(void* const* d_in, const int* in_sizes, int n_in,
                              void* d_out, int out_size, void* d_ws, size_t ws_size,
                              hipStream_t stream) {
    const float* x  = (const float*)d_in[0];   // (2, 48, 64, 64, 64) f32
    const float* fw = (const float*)d_in[1];   // (1, 144) f32
    const float* fb = (const float*)d_in[2];   // (1,) f32
    float* out = (float*)d_out;                // (2, 1, 64, 64, 64) f32

    float* ws0 = (float*)d_ws;                 // 3*VOL floats = 6.29 MB
    float* ws1 = ws0 + (size_t)NS * VOL;       // another 6.29 MB

    // A: channel mix + W box-sum -> ws0  (reads x once)
    k_chanred_wpool<<<(NB * DIM * DIM) / ROWS, 256, 0, stream>>>(x, fw, ws0);
    // B: box along H -> ws1
    k_poolh<<<(NS * VOL / 4) / 256, 256, 0, stream>>>(ws0, ws1);
    // C: box along D + scale + bias + sigmoid -> out
    k_poold_fuse<<<(VOL / 4) / 256, 256, 0, stream>>>(ws1, fb, out);
}

// Round 4
// 31.562 us; speedup vs baseline: 1.2221x; 1.0406x over previous
//
#include <hip/hip_runtime.h>
#include <math.h>

// Problem geometry (fixed by the reference setup)
#define CH       48
#define DIM      64
#define SPATIAL  (DIM * DIM * DIM)   // 262144 per (b, c)
#define NB       2
#define VOL      (NB * SPATIAL)      // 524288 per scale volume
#define NS       3
#define ROWS     16                  // W-rows per block in kernel A
#define ZT_PLANE 4096                // (d,h) plane in f4 units, per (s,b,w4)
#define DT       8                   // d-tile in kernel B
#define DTH      (DT + 6)            // with +-3 halo

typedef float f4 __attribute__((ext_vector_type(4)));

// -------------------------------------------------------------------------
// A: channel reduction + W box-sum, fused; writes TRANSPOSED zT[s][b][w4][d][h].
// Block = 256 threads = 16 rows x 16 lanes (each lane owns a float4 of W).
// x is read exactly once (100.7 MB, non-temporal, fully coalesced 1KB/wave).
// -------------------------------------------------------------------------
__global__ __launch_bounds__(256) void kA(
        const float* __restrict__ x,
        const float* __restrict__ fw,
        float* __restrict__ zt) {
    __shared__ float sw[NS * CH];
    __shared__ f4 tile[NS][ROWS][16];        // 12 KB
    const int tid = threadIdx.x;
    if (tid < NS * CH) sw[tid] = fw[tid];
    __syncthreads();

    const int lr  = tid >> 4;                // row in block, 0..15
    const int lw  = tid & 15;                // float4 index along W, 0..15
    const int row = blockIdx.x * ROWS + lr;  // b*4096 + d*64 + h
    const int b   = row >> 12;
    const int dh  = row & 4095;              // d*64 + h

    const f4* xp = (const f4*)x
        + (size_t)b * CH * (SPATIAL / 4)
        + (size_t)dh * 16 + lw;

    f4 a0 = {0,0,0,0}, a1 = {0,0,0,0}, a2 = {0,0,0,0};
    #pragma unroll 8
    for (int c = 0; c < CH; ++c) {
        f4 v = __builtin_nontemporal_load(&xp[(size_t)c * (SPATIAL / 4)]);
        a0 += sw[c] * v;
        a1 += sw[CH + c] * v;
        a2 += sw[2 * CH + c] * v;
    }
    tile[0][lr][lw] = a0;
    tile[1][lr][lw] = a1;
    tile[2][lr][lw] = a2;
    __syncthreads();

    f4* zt4 = (f4*)zt;
    const f4 zero = {0,0,0,0};
    #pragma unroll
    for (int s = 0; s < NS; ++s) {
        // 12-float window around this lane's 4 outputs; zero past row ends
        // == reference zero padding (count_include_pad).
        f4 m1 = (lw > 0)  ? tile[s][lr][lw - 1] : zero;
        f4 m0 = tile[s][lr][lw];
        f4 p1 = (lw < 15) ? tile[s][lr][lw + 1] : zero;
        float f[12] = {m1.x, m1.y, m1.z, m1.w,
                       m0.x, m0.y, m0.z, m0.w,
                       p1.x, p1.y, p1.z, p1.w};
        const int p = s + 1;
        f4 r;
        #pragma unroll
        for (int j = 0; j < 4; ++j) {
            float acc = 0.f;
            #pragma unroll
            for (int i = -3; i <= 3; ++i)
                if (i >= -p && i <= p) acc += f[4 + j + i];
            r[j] = acc;
        }
        // transposed store: zT[s][b][lw][d][h]  (64B-granule scatter per wave)
        zt4[((size_t)(s * NB + b) * 16 + lw) * ZT_PLANE + dh] = r;
    }
}

// -------------------------------------------------------------------------
// B: fused H box-sum + D box-sum + 1/k^3 + cross-scale sum + bias + sigmoid.
// Block = (b, w4, d0-tile): loads zT tile (3 scales x 14 d x 64 h f4, 43 KB)
// with fully-contiguous reads, H-pools in place (regs across a barrier),
// D-pools from LDS and writes the final output.
// -------------------------------------------------------------------------
__global__ __launch_bounds__(256) void kB(
        const float* __restrict__ zt,
        const float* __restrict__ fb,
        float* __restrict__ out) {
    __shared__ f4 tile[NS][DTH][DIM];        // 2688 f4 = 43 KB
    const int tid = threadIdx.x;
    const int bid = blockIdx.x;              // 2*16*8 = 256 blocks
    const int w4  = bid & 15;
    const int d0  = ((bid >> 4) & 7) * DT;
    const int b   = bid >> 7;

    const f4* zt4 = (const f4*)zt;
    #pragma unroll
    for (int s = 0; s < NS; ++s) {
        const f4* src = zt4 + ((size_t)(s * NB + b) * 16 + w4) * ZT_PLANE;
        #pragma unroll
        for (int t = 0; t < (DTH * DIM + 255) / 256; ++t) {
            int i = tid + t * 256;
            if (i < DTH * DIM) {
                int dd = i >> 6, h = i & 63;
                int gd = d0 - 3 + dd;
                f4 v = {0,0,0,0};
                if (gd >= 0 && gd < DIM) v = src[gd * 64 + h];
                tile[s][dd][h] = v;          // zero-filled halo == zero padding
            }
        }
    }
    __syncthreads();

    // H-pool in place: compute all windows into regs, barrier, write back.
    const int NITEM = NS * DTH * DIM;        // 2688
    f4 acc[11];                              // fixed-trip unrolled -> stays in VGPRs
    #pragma unroll
    for (int t = 0; t < 11; ++t) {
        int j = tid + t * 256;
        f4 a = {0,0,0,0};
        if (j < NITEM) {
            int s   = j / (DTH * DIM);
            int rem = j - s * (DTH * DIM);
            int dd  = rem >> 6, h = rem & 63;
            int p   = s + 1;
            int lo  = h - p; if (lo < 0)  lo = 0;
            int hi  = h + p; if (hi > 63) hi = 63;
            for (int hh = lo; hh <= hi; ++hh) a += tile[s][dd][hh];
        }
        acc[t] = a;
    }
    __syncthreads();
    #pragma unroll
    for (int t = 0; t < 11; ++t) {
        int j = tid + t * 256;
        if (j < NITEM) {
            int s   = j / (DTH * DIM);
            int rem = j - s * (DTH * DIM);
            tile[s][rem >> 6][rem & 63] = acc[t];
        }
    }
    __syncthreads();

    // D-pool + combine scales + bias + sigmoid -> final output.
    const float inv[NS] = {1.f / 27.f, 1.f / 125.f, 1.f / 343.f};
    const float bias = fb[0];
    f4* out4 = (f4*)out;
    #pragma unroll
    for (int t = 0; t < DT * DIM / 256; ++t) {   // 2 iters
        int j   = tid + t * 256;
        int ddp = j >> 6, h = j & 63;
        int d   = d0 + ddp;
        f4 a2 = {bias, bias, bias, bias};
        #pragma unroll
        for (int s = 0; s < NS; ++s) {
            int p = s + 1;
            f4 a = {0,0,0,0};
            for (int i = -3; i <= 3; ++i)        // halo rows already zero
                if (i >= -p && i <= p) a += tile[s][ddp + 3 + i][h];
            a2 += a * inv[s];
        }
        f4 r;
        #pragma unroll
        for (int jj = 0; jj < 4; ++jj) r[jj] = 1.f / (1.f + __expf(-a2[jj]));
        out4[(size_t)b * (SPATIAL / 4) + (size_t)d * 1024 + h * 16 + w4] = r;
    }
}

// -------------------------------------------------------------------------
extern "C" void kernel_launch(void* const* d_in, const int* in_sizes, int n_in,
                              void* d_out, int out_size, void* d_ws, size_t ws_size,
                              hipStream_t stream) {
    const float* x  = (const float*)d_in[0];   // (2, 48, 64, 64, 64) f32
    const float* fw = (const float*)d_in[1];   // (1, 144) f32
    const float* fb = (const float*)d_in[2];   // (1,) f32
    float* out = (float*)d_out;                // (2, 1, 64, 64, 64) f32

    float* zt = (float*)d_ws;                  // 3*VOL floats = 6.29 MB

    // A: channel mix + W box-sum -> zT (transposed)
    kA<<<(NB * DIM * DIM * DIM / ROWS) / 64, 256, 0, stream>>>(x, fw, zt);
    // B: H-pool + D-pool + scale + bias + sigmoid -> out
    kB<<<NB * 16 * (DIM / DT), 256, 0, stream>>>(zt, fb, out);
}